// Round 7
// baseline (149.239 us; speedup 1.0000x reference)
//
#include <hip/hip_runtime.h>

#define NE 100000   // edges
#define NN 50000    // nodes

typedef short short8 __attribute__((ext_vector_type(8)));
typedef float f32x4 __attribute__((ext_vector_type(4)));
typedef unsigned short ushort;
typedef unsigned int uint;

// fp32 -> bf16 bits, round-to-nearest-even
__device__ inline ushort f2bf(float f) {
    unsigned int u = __float_as_uint(f);
    u += 0x7FFFu + ((u >> 16) & 1u);
    return (ushort)(u >> 16);
}
__device__ inline float bf2f(ushort u) {
    return __uint_as_float((unsigned int)u << 16);
}

__device__ inline short8 pack_bf8(float4 a, float4 b) {
    short8 r;
    r[0] = (short)f2bf(a.x); r[1] = (short)f2bf(a.y);
    r[2] = (short)f2bf(a.z); r[3] = (short)f2bf(a.w);
    r[4] = (short)f2bf(b.x); r[5] = (short)f2bf(b.y);
    r[6] = (short)f2bf(b.z); r[7] = (short)f2bf(b.w);
    return r;
}

// ---------------------------------------------------------------------------
// Prep (single launch): pack both layers' QKV + Wo weights into bf16
// B-fragment order.
// qkv: wf[((s*12 + t)*64 + lane)*8 + j] = W[k=32s+(lane>>4)*8+j][n=16t+(lane&15)]
// ---------------------------------------------------------------------------
__device__ inline void pack_qkv_slot(int slot, const float* Wq, const float* Wk,
                                     const float* Wv, ushort* wf)
{
    int lane = slot & 63;
    int st = slot >> 6;
    int s = st / 12, t = st % 12;
    int n = t * 16 + (lane & 15);
    int kb = s * 32 + (lane >> 4) * 8;
    const float* w = (n < 64) ? Wq : (n < 128) ? Wk : Wv;
    int nn = n & 63;
    #pragma unroll
    for (int j = 0; j < 8; ++j)
        wf[(size_t)slot * 8 + j] = f2bf(w[(size_t)(kb + j) * 64 + nn]);
}

__device__ inline void pack_wo_slot(int slot, const float* Wo, ushort* wf)
{
    int lane = slot & 63;
    int st = slot >> 6;
    int s = st / 4, t = st % 4;
    int n = t * 16 + (lane & 15);
    int kb = s * 32 + (lane >> 4) * 8;
    #pragma unroll
    for (int j = 0; j < 8; ++j)
        wf[(size_t)slot * 8 + j] = f2bf(Wo[(size_t)(kb + j) * 64 + n]);
}

__global__ __launch_bounds__(256) void prep_all(
    const float* __restrict__ l1Wq, const float* __restrict__ l1Wk,
    const float* __restrict__ l1Wv, const float* __restrict__ l1Wo,
    const float* __restrict__ l2Wq, const float* __restrict__ l2Wk,
    const float* __restrict__ l2Wv, const float* __restrict__ l2Wo,
    ushort* __restrict__ wf1, ushort* __restrict__ wf2,
    ushort* __restrict__ wo1, ushort* __restrict__ wo2)
{
    int idx = blockIdx.x * 256 + threadIdx.x;
    if (idx < 4608)            pack_qkv_slot(idx,         l1Wq, l1Wk, l1Wv, wf1);
    else if (idx < 9216)       pack_qkv_slot(idx - 4608,  l2Wq, l2Wk, l2Wv, wf2);
    else if (idx < 9728)       pack_wo_slot (idx - 9216,  l1Wo, wo1);
    else if (idx < 10240)      pack_wo_slot (idx - 9728,  l2Wo, wo2);
}

// ---------------------------------------------------------------------------
// QKV GEMM via MFMA — fully scalarized (NO indexed register arrays anywhere).
// Block = 256 threads / 4 waves = 64 edge-rows; wave = 16 rows x 192 cols.
// B panel staged K-phase by K-phase (24 KB LDS) via global_load_lds(16).
// A fragments packed up-front into 6 named short8 regs.
// ---------------------------------------------------------------------------
#define MFMA_B16(a, b, c) c = __builtin_amdgcn_mfma_f32_16x16x32_bf16(a, b, c, 0, 0, 0)

#define GLP const __attribute__((address_space(1))) uint*
#define LDP __attribute__((address_space(3))) uint*

// stage the 24 local fragments of phase `ph` (wave w takes lf = w*6 .. w*6+5)
#define STAGE(ph) do {                                                         \
    const char* gs_ = (const char*)wfrag + (size_t)(ph) * 24576 + (size_t)l * 16; \
    __builtin_amdgcn_global_load_lds((GLP)(gs_ + (size_t)(w*6+0)*1024), (LDP)(ldsb + (size_t)(w*6+0)*1024), 16, 0, 0); \
    __builtin_amdgcn_global_load_lds((GLP)(gs_ + (size_t)(w*6+1)*1024), (LDP)(ldsb + (size_t)(w*6+1)*1024), 16, 0, 0); \
    __builtin_amdgcn_global_load_lds((GLP)(gs_ + (size_t)(w*6+2)*1024), (LDP)(ldsb + (size_t)(w*6+2)*1024), 16, 0, 0); \
    __builtin_amdgcn_global_load_lds((GLP)(gs_ + (size_t)(w*6+3)*1024), (LDP)(ldsb + (size_t)(w*6+3)*1024), 16, 0, 0); \
    __builtin_amdgcn_global_load_lds((GLP)(gs_ + (size_t)(w*6+4)*1024), (LDP)(ldsb + (size_t)(w*6+4)*1024), 16, 0, 0); \
    __builtin_amdgcn_global_load_lds((GLP)(gs_ + (size_t)(w*6+5)*1024), (LDP)(ldsb + (size_t)(w*6+5)*1024), 16, 0, 0); \
} while (0)

// one K-step: 12 named B frags from LDS sub-panel si, 12 MFMAs into c0..c11
#define KSTEP(Areg, si) do {                                                   \
    const char* lb_ = ldsb + (size_t)(si) * 12288 + (size_t)l * 16;            \
    short8 b0_  = *(const short8*)(lb_ + 0);                                   \
    short8 b1_  = *(const short8*)(lb_ + 1024);                                \
    short8 b2_  = *(const short8*)(lb_ + 2048);                                \
    short8 b3_  = *(const short8*)(lb_ + 3072);                                \
    short8 b4_  = *(const short8*)(lb_ + 4096);                                \
    short8 b5_  = *(const short8*)(lb_ + 5120);                                \
    short8 b6_  = *(const short8*)(lb_ + 6144);                                \
    short8 b7_  = *(const short8*)(lb_ + 7168);                                \
    short8 b8_  = *(const short8*)(lb_ + 8192);                                \
    short8 b9_  = *(const short8*)(lb_ + 9216);                                \
    short8 b10_ = *(const short8*)(lb_ + 10240);                               \
    short8 b11_ = *(const short8*)(lb_ + 11264);                               \
    MFMA_B16(Areg, b0_,  c0);  MFMA_B16(Areg, b1_,  c1);                       \
    MFMA_B16(Areg, b2_,  c2);  MFMA_B16(Areg, b3_,  c3);                       \
    MFMA_B16(Areg, b4_,  c4);  MFMA_B16(Areg, b5_,  c5);                       \
    MFMA_B16(Areg, b6_,  c6);  MFMA_B16(Areg, b7_,  c7);                       \
    MFMA_B16(Areg, b8_,  c8);  MFMA_B16(Areg, b9_,  c9);                       \
    MFMA_B16(Areg, b10_, c10); MFMA_B16(Areg, b11_, c11);                      \
} while (0)

// store one n-tile t (literal) from named acc reg into dst (q/k/v picked at
// compile time via the literal t)
#define STORE_T(creg, dstp, cloc) do {                                         \
    ushort* dp_ = (dstp) + (cloc);                                             \
    int row_ = e0 + kg * 4;                                                    \
    if (row_ + 0 < NE) dp_[(size_t)(row_ + 0) * 64] = f2bf(creg[0]);           \
    if (row_ + 1 < NE) dp_[(size_t)(row_ + 1) * 64] = f2bf(creg[1]);           \
    if (row_ + 2 < NE) dp_[(size_t)(row_ + 2) * 64] = f2bf(creg[2]);           \
    if (row_ + 3 < NE) dp_[(size_t)(row_ + 3) * 64] = f2bf(creg[3]);           \
} while (0)

__global__ __launch_bounds__(256) void qkv_mfma(
    const float* __restrict__ ef, const float* __restrict__ nodef,
    const int* __restrict__ eidx, const ushort* __restrict__ wfrag,
    ushort* __restrict__ qo, ushort* __restrict__ ko, ushort* __restrict__ vo)
{
    __shared__ __align__(1024) char ldsb[24 * 1024];

    const int tid = threadIdx.x;
    const int l   = tid & 63;
    const int w   = tid >> 6;
    const int r   = l & 15;
    const int kg  = l >> 4;
    const int e0  = blockIdx.x * 64 + w * 16;
    const int e   = e0 + r;
    const int ec  = (e < NE) ? e : NE - 1;

    // kick off phase-0 B staging immediately
    STAGE(0);

    const int koff = kg * 8;
    const float* rp0 = ef    + (size_t)ec * 64;
    const float* rp1 = nodef + (size_t)eidx[ec] * 64;
    const float* rp2 = nodef + (size_t)eidx[NE + ec] * 64;

    // all 6 A fragments, named regs, packed up front
    short8 A0 = pack_bf8(*(const float4*)(rp0 + koff),      *(const float4*)(rp0 + koff + 4));
    short8 A1 = pack_bf8(*(const float4*)(rp0 + 32 + koff), *(const float4*)(rp0 + 36 + koff));
    short8 A2 = pack_bf8(*(const float4*)(rp1 + koff),      *(const float4*)(rp1 + koff + 4));
    short8 A3 = pack_bf8(*(const float4*)(rp1 + 32 + koff), *(const float4*)(rp1 + 36 + koff));
    short8 A4 = pack_bf8(*(const float4*)(rp2 + koff),      *(const float4*)(rp2 + koff + 4));
    short8 A5 = pack_bf8(*(const float4*)(rp2 + 32 + koff), *(const float4*)(rp2 + 36 + koff));

    f32x4 c0 = (f32x4)(0.f), c1 = (f32x4)(0.f), c2  = (f32x4)(0.f), c3  = (f32x4)(0.f);
    f32x4 c4 = (f32x4)(0.f), c5 = (f32x4)(0.f), c6  = (f32x4)(0.f), c7  = (f32x4)(0.f);
    f32x4 c8 = (f32x4)(0.f), c9 = (f32x4)(0.f), c10 = (f32x4)(0.f), c11 = (f32x4)(0.f);

    __syncthreads();          // phase-0 B in LDS
    KSTEP(A0, 0);
    KSTEP(A1, 1);
    __syncthreads();          // done reading phase-0
    STAGE(1);
    __syncthreads();          // phase-1 B in LDS
    KSTEP(A2, 0);
    KSTEP(A3, 1);
    __syncthreads();          // done reading phase-1
    STAGE(2);
    __syncthreads();          // phase-2 B in LDS
    KSTEP(A4, 0);
    KSTEP(A5, 1);

    // stores: n-tile t -> col t*16+r; t 0-3 = q, 4-7 = k, 8-11 = v
    STORE_T(c0,  qo, 0 * 16 + r);
    STORE_T(c1,  qo, 1 * 16 + r);
    STORE_T(c2,  qo, 2 * 16 + r);
    STORE_T(c3,  qo, 3 * 16 + r);
    STORE_T(c4,  ko, 0 * 16 + r);
    STORE_T(c5,  ko, 1 * 16 + r);
    STORE_T(c6,  ko, 2 * 16 + r);
    STORE_T(c7,  ko, 3 * 16 + r);
    STORE_T(c8,  vo, 0 * 16 + r);
    STORE_T(c9,  vo, 1 * 16 + r);
    STORE_T(c10, vo, 2 * 16 + r);
    STORE_T(c11, vo, 3 * 16 + r);
}

// ---------------------------------------------------------------------------
// Attention: one wave per dst edge (neighbors at adj slots e*8..e*8+7).
// lane = half*32 + h*8 + dd: dim-pair (2dd,2dd+1) of head h; half owns
// neighbors {4*half..4*half+3} (order-invariant). bf16 in/out, fp32 math.
// ---------------------------------------------------------------------------
__global__ __launch_bounds__(256) void attn_kernel(
    const ushort* __restrict__ q, const ushort* __restrict__ kbuf,
    const ushort* __restrict__ vbuf, const int* __restrict__ adj_src,
    ushort* __restrict__ ao)
{
    const int wid  = (blockIdx.x * 256 + threadIdx.x) >> 6;
    const int lane = threadIdx.x & 63;
    if (wid >= NE) return;
    const int e    = wid;
    const int half = lane >> 5;
    const int l32  = lane & 31;

    const int4 nb = *(const int4*)(adj_src + e * 8 + half * 4);
    const int nbr0 = nb.x, nbr1 = nb.y, nbr2 = nb.z, nbr3 = nb.w;

    ushort2 qu = *(const ushort2*)(q + (size_t)e * 64 + l32 * 2);
    const float q0 = bf2f(qu.x), q1 = bf2f(qu.y);

    ushort2 ku0 = *(const ushort2*)(kbuf + (size_t)nbr0 * 64 + l32 * 2);
    ushort2 ku1 = *(const ushort2*)(kbuf + (size_t)nbr1 * 64 + l32 * 2);
    ushort2 ku2 = *(const ushort2*)(kbuf + (size_t)nbr2 * 64 + l32 * 2);
    ushort2 ku3 = *(const ushort2*)(kbuf + (size_t)nbr3 * 64 + l32 * 2);
    ushort2 vu0 = *(const ushort2*)(vbuf + (size_t)nbr0 * 64 + l32 * 2);
    ushort2 vu1 = *(const ushort2*)(vbuf + (size_t)nbr1 * 64 + l32 * 2);
    ushort2 vu2 = *(const ushort2*)(vbuf + (size_t)nbr2 * 64 + l32 * 2);
    ushort2 vu3 = *(const ushort2*)(vbuf + (size_t)nbr3 * 64 + l32 * 2);

    float s0 = q0 * bf2f(ku0.x) + q1 * bf2f(ku0.y);
    float s1 = q0 * bf2f(ku1.x) + q1 * bf2f(ku1.y);
    float s2 = q0 * bf2f(ku2.x) + q1 * bf2f(ku2.y);
    float s3 = q0 * bf2f(ku3.x) + q1 * bf2f(ku3.y);
    s0 += __shfl_xor(s0, 1); s0 += __shfl_xor(s0, 2); s0 += __shfl_xor(s0, 4);
    s1 += __shfl_xor(s1, 1); s1 += __shfl_xor(s1, 2); s1 += __shfl_xor(s1, 4);
    s2 += __shfl_xor(s2, 1); s2 += __shfl_xor(s2, 2); s2 += __shfl_xor(s2, 4);
    s3 += __shfl_xor(s3, 1); s3 += __shfl_xor(s3, 2); s3 += __shfl_xor(s3, 4);
    s0 *= 0.25f; s1 *= 0.25f; s2 *= 0.25f; s3 *= 0.25f;

    float m = fmaxf(fmaxf(s0, s1), fmaxf(s2, s3));
    m = fmaxf(m, __shfl_xor(m, 32));
    float w0 = __expf(s0 - m), w1 = __expf(s1 - m);
    float w2 = __expf(s2 - m), w3 = __expf(s3 - m);
    float den = w0 + w1 + w2 + w3;
    den += __shfl_xor(den, 32);
    const float inv = 1.f / den;

    float ox = 0.f, oy = 0.f;
    ox = fmaf(w0, bf2f(vu0.x), ox); oy = fmaf(w0, bf2f(vu0.y), oy);
    ox = fmaf(w1, bf2f(vu1.x), ox); oy = fmaf(w1, bf2f(vu1.y), oy);
    ox = fmaf(w2, bf2f(vu2.x), ox); oy = fmaf(w2, bf2f(vu2.y), oy);
    ox = fmaf(w3, bf2f(vu3.x), ox); oy = fmaf(w3, bf2f(vu3.y), oy);
    ox = (ox + __shfl_xor(ox, 32)) * inv;
    oy = (oy + __shfl_xor(oy, 32)) * inv;

    if (lane < 32) {
        ushort2 o;
        o.x = f2bf(ox);
        o.y = f2bf(oy);
        *(ushort2*)(ao + (size_t)e * 64 + l32 * 2) = o;
    }
}

// ---------------------------------------------------------------------------
// Wo GEMM via MFMA + fused residual: out = ef_in + attn(bf16) @ Wo.
// One wave per 16 rows x 64 cols. B-buffer is 8 KB -> L1/L2-resident.
// ---------------------------------------------------------------------------
__global__ __launch_bounds__(256) void wo_mfma(
    const float* __restrict__ ef_in, const ushort* __restrict__ attn,
    const ushort* __restrict__ wofrag, float* __restrict__ efo)
{
    const int wave = threadIdx.x >> 6;
    const int lane = threadIdx.x & 63;
    const int r  = lane & 15;
    const int kg = lane >> 4;
    const int e0 = blockIdx.x * 64 + wave * 16;
    const int e  = e0 + r;
    const int ec = (e < NE) ? e : NE - 1;

    short8 af0 = *(const short8*)(attn + (size_t)ec * 64 + kg * 8);
    short8 af1 = *(const short8*)(attn + (size_t)ec * 64 + 32 + kg * 8);

    const char* wf = (const char*)wofrag + (size_t)lane * 16;
    f32x4 d0 = (f32x4)(0.f), d1 = (f32x4)(0.f), d2 = (f32x4)(0.f), d3 = (f32x4)(0.f);
    short8 g0 = *(const short8*)(wf + 0 * 1024);
    short8 g1 = *(const short8*)(wf + 1 * 1024);
    short8 g2 = *(const short8*)(wf + 2 * 1024);
    short8 g3 = *(const short8*)(wf + 3 * 1024);
    MFMA_B16(af0, g0, d0); MFMA_B16(af0, g1, d1);
    MFMA_B16(af0, g2, d2); MFMA_B16(af0, g3, d3);
    g0 = *(const short8*)(wf + 4 * 1024);
    g1 = *(const short8*)(wf + 5 * 1024);
    g2 = *(const short8*)(wf + 6 * 1024);
    g3 = *(const short8*)(wf + 7 * 1024);
    MFMA_B16(af1, g0, d0); MFMA_B16(af1, g1, d1);
    MFMA_B16(af1, g2, d2); MFMA_B16(af1, g3, d3);

    const int orow = e0 + kg * 4;
    #pragma unroll
    for (int t = 0; t < 4; ++t) {
        const f32x4 dd = (t == 0) ? d0 : (t == 1) ? d1 : (t == 2) ? d2 : d3;
        const int c = t * 16 + r;
        #pragma unroll
        for (int j = 0; j < 4; ++j) {
            int row = orow + j;
            if (row < NE) {
                size_t off = (size_t)row * 64 + c;
                efo[off] = dd[j] + ef_in[off];
            }
        }
    }
}

// ---------------------------------------------------------------------------
extern "C" void kernel_launch(void* const* d_in, const int* in_sizes, int n_in,
                              void* d_out, int out_size, void* d_ws, size_t ws_size,
                              hipStream_t stream)
{
    const float* nodef   = (const float*)d_in[0];
    const float* ef      = (const float*)d_in[1];
    const int*   eidx    = (const int*)d_in[2];   // [2,E]
    const int*   adj_src = (const int*)d_in[4];
    const float* l1Wq = (const float*)d_in[6];
    const float* l1Wk = (const float*)d_in[7];
    const float* l1Wv = (const float*)d_in[8];
    const float* l1Wo = (const float*)d_in[9];
    const float* l2Wq = (const float*)d_in[10];
    const float* l2Wk = (const float*)d_in[11];
    const float* l2Wv = (const float*)d_in[12];
    const float* l2Wo = (const float*)d_in[13];

    ushort* q  = (ushort*)d_ws;                  // [E,64] bf16
    ushort* k  = q  + (size_t)NE * 64;
    ushort* v  = k  + (size_t)NE * 64;
    ushort* ao = v  + (size_t)NE * 64;           // attn out, bf16
    ushort* wf1 = ao + (size_t)NE * 64;          // 36864 ushorts each
    ushort* wf2 = wf1 + 36864;
    ushort* wo1 = wf2 + 36864;                   // 4096 each
    ushort* wo2 = wo1 + 4096;
    float* out = (float*)d_out;

    dim3 blk(256);
    const int gq = (NE + 63) / 64;    // 1563 (64 rows / block, 4 indep waves)
    const int ga = (NE + 3) / 4;      // 25000
    const int gw = (NE + 63) / 64;    // 1563

    prep_all<<<40, blk, 0, stream>>>(l1Wq, l1Wk, l1Wv, l1Wo,
                                     l2Wq, l2Wk, l2Wv, l2Wo,
                                     wf1, wf2, wo1, wo2);

    // ---- layer 1 ----
    qkv_mfma<<<gq, blk, 0, stream>>>(ef, nodef, eidx, wf1, q, k, v);
    attn_kernel<<<ga, blk, 0, stream>>>(q, k, v, adj_src, ao);
    wo_mfma<<<gw, blk, 0, stream>>>(ef, ao, wo1, out);
    // ---- layer 2 ----
    qkv_mfma<<<gq, blk, 0, stream>>>(out, nodef, eidx, wf2, q, k, v);
    attn_kernel<<<ga, blk, 0, stream>>>(q, k, v, adj_src, ao);
    wo_mfma<<<gw, blk, 0, stream>>>(out, ao, wo2, out);
}